// Round 2
// baseline (106.930 us; speedup 1.0000x reference)
//
#include <hip/hip_runtime.h>
#include <stdint.h>

// Problem constants (fixed by setup_inputs)
#define TOKENS 64
#define IN_F   4096
#define OUT_F  11008
#define RANK   16
#define GS     128
#define NG     32
#define ZCOLS  (OUT_F / 8)
#define LORA_SCALE 2.0f

using short8  = __attribute__((ext_vector_type(8))) short;
using float4v = __attribute__((ext_vector_type(4))) float;

// round-to-nearest-even fp32 -> bf16 bits; also returns the rounded-back fp32
static __device__ inline uint16_t f2bf(float f, float* back) {
    uint32_t u = __float_as_uint(f);
    uint32_t r = (u + 0x7FFFu + ((u >> 16) & 1u)) >> 16;
    *back = __uint_as_float(r << 16);
    return (uint16_t)r;
}

// ---------------------------------------------------------------------------
// K1: per token t (64 blocks):
//   xf (MFMA-fragment order) = bf16(x)  — xf4[(mt*128 + kchunk)*64 + quad*16 + n]
//   xsumT[g][t] = sum over group g of bf16-rounded x   (GPTQ zero fold)
//   midT[j][t]  = sum_k x[t][k] * lora_A[j][k]         (fp32 LoRA mid)
// ---------------------------------------------------------------------------
__global__ __launch_bounds__(256) void prep_kernel(
        const float* __restrict__ x,
        const float* __restrict__ loraA,
        uint4* __restrict__ xf4,
        float* __restrict__ xsumT,
        float* __restrict__ midT) {
    __shared__ float redg[256];
    __shared__ float redm[4][16];
    const int t    = blockIdx.x;
    const int tid  = threadIdx.x;
    const int lane = tid & 63;
    const int wv   = tid >> 6;

    float4 xv[4];
    const float4* xp = (const float4*)(x + (size_t)t * IN_F + tid * 16);
    #pragma unroll
    for (int i = 0; i < 4; ++i) xv[i] = xp[i];

    union { uint16_t u[16]; uint4 q[2]; } ob;
    float s = 0.f;
    #pragma unroll
    for (int i = 0; i < 4; ++i) {
        float b;
        ob.u[i * 4 + 0] = f2bf(xv[i].x, &b); s += b;
        ob.u[i * 4 + 1] = f2bf(xv[i].y, &b); s += b;
        ob.u[i * 4 + 2] = f2bf(xv[i].z, &b); s += b;
        ob.u[i * 4 + 3] = f2bf(xv[i].w, &b); s += b;
    }
    // scatter into fragment order
    {
        const int mm = t >> 4, nn = t & 15;
        const int kchunk = tid >> 1;
        #pragma unroll
        for (int i = 0; i < 2; ++i) {
            const int qd = (tid * 2 + i) & 3;
            xf4[(size_t)((mm * 128 + kchunk) * 64 + qd * 16 + nn)] = ob.q[i];
        }
    }
    redg[tid] = s;

    // LoRA mid partials
    float pj[16];
    #pragma unroll
    for (int j = 0; j < 16; ++j) {
        const float4* ap = (const float4*)(loraA + (size_t)j * IN_F + tid * 16);
        float ps = 0.f;
        #pragma unroll
        for (int i = 0; i < 4; ++i) {
            float4 a = ap[i];
            ps += a.x * xv[i].x + a.y * xv[i].y + a.z * xv[i].z + a.w * xv[i].w;
        }
        pj[j] = ps;
    }
    #pragma unroll
    for (int j = 0; j < 16; ++j) {
        #pragma unroll
        for (int off = 32; off; off >>= 1) pj[j] += __shfl_down(pj[j], off);
    }
    if (lane == 0) {
        #pragma unroll
        for (int j = 0; j < 16; ++j) redm[wv][j] = pj[j];
    }
    __syncthreads();
    if (tid < NG) {
        float g = 0.f;
        #pragma unroll
        for (int i = 0; i < 8; ++i) g += redg[tid * 8 + i];
        xsumT[tid * TOKENS + t] = g;
    }
    if (tid < 16)
        midT[tid * TOKENS + t] = redm[0][tid] + redm[1][tid] + redm[2][tid] + redm[3][tid];
}

// ---------------------------------------------------------------------------
// K2: out[t][o] = LORA_SCALE * sum_j midT[j][t] * loraB[o][j]
// Pre-initializes out (poisoned by harness) before K3's split-K atomics.
// ---------------------------------------------------------------------------
__global__ __launch_bounds__(256) void lora_out_kernel(
        const float* __restrict__ midT,
        const float* __restrict__ loraB,
        float* __restrict__ out) {
    const int gid = blockIdx.x * 256 + threadIdx.x;
    const int t = gid / OUT_F;
    const int o = gid - t * OUT_F;
    const float4* b4 = (const float4*)(loraB + (size_t)o * RANK);
    float s = 0.f;
    #pragma unroll
    for (int i = 0; i < 4; ++i) {
        float4 b = b4[i];
        s += b.x * midT[(i * 4 + 0) * TOKENS + t];
        s += b.y * midT[(i * 4 + 1) * TOKENS + t];
        s += b.z * midT[(i * 4 + 2) * TOKENS + t];
        s += b.w * midT[(i * 4 + 3) * TOKENS + t];
    }
    out[gid] = s * LORA_SCALE;
}

// ---------------------------------------------------------------------------
// K3: GPTQ-dequant GEMM, split-K=4, zero LDS / zero barriers.
// Block 256 = 4 waves: wave = (M-half mh: 2 M-tiles = 32 tokens) x
// (col-slice cs: 32 cols), over kseg's 8 groups. blockIdx.x = colblk*4 + kseg.
// Same-mh waves share A via L1; same-cs waves share B via L1.
// Each dequanted B word feeds 2 MFMAs (both M-tiles). Depth-2 rings.
// Partials combined with fp32 atomicAdd onto LoRA-initialized out.
// ---------------------------------------------------------------------------
#define LOADG(st, g) do {                                                       \
    _Pragma("unroll")                                                           \
    for (int mt = 0; mt < 2; ++mt)                                              \
        _Pragma("unroll")                                                       \
        for (int ks = 0; ks < 4; ++ks)                                          \
            A[st][mt * 4 + ks] =                                                \
                xf4[(size_t)(((mh * 2 + mt) * 128 + (g) * 4 + ks) * 64) + lane];\
    _Pragma("unroll")                                                           \
    for (int ks = 0; ks < 4; ++ks)                                              \
        _Pragma("unroll")                                                       \
        for (int nh = 0; nh < 2; ++nh)                                          \
            B[st][ks * 2 + nh] =                                                \
                qwc[(size_t)((g) * 16 + ks * 4 + quad) * OUT_F + nh * 16];      \
    _Pragma("unroll")                                                           \
    for (int mt = 0; mt < 2; ++mt)                                              \
        XS[st][mt] = *(const float4*)(xsumT + (g) * 64 +                        \
                                      (mh * 2 + mt) * 16 + quad * 4);           \
    _Pragma("unroll")                                                           \
    for (int nh = 0; nh < 2; ++nh) {                                            \
        S[st][nh] = scales[(size_t)(g) * OUT_F + col0 + nh * 16 + n];           \
        Z[st][nh] = qz[(size_t)(g) * ZCOLS + ((col0 + nh * 16 + n) >> 3)];      \
    }                                                                           \
} while (0)

#define COMPUTEG(st) do {                                                       \
    float4v accg[2][2];                                                         \
    _Pragma("unroll")                                                           \
    for (int mt = 0; mt < 2; ++mt)                                              \
        _Pragma("unroll")                                                       \
        for (int nh = 0; nh < 2; ++nh)                                          \
            accg[mt][nh] = (float4v){0.f, 0.f, 0.f, 0.f};                       \
    _Pragma("unroll")                                                           \
    for (int ks = 0; ks < 4; ++ks) {                                            \
        union { uint4 u; short8 s; } af0, af1;                                  \
        af0.u = A[st][ks];                                                      \
        af1.u = A[st][4 + ks];                                                  \
        _Pragma("unroll")                                                       \
        for (int nh = 0; nh < 2; ++nh) {                                        \
            uint32_t q  = B[st][ks * 2 + nh];                                   \
            uint32_t lo = q & 0x0F0F0F0Fu;                                      \
            uint32_t hi = (q >> 4) & 0x0F0F0F0Fu;                               \
            union { uint32_t u32[4]; short8 s8; } bf;                           \
            _Pragma("unroll")                                                   \
            for (int i = 0; i < 4; ++i)                                         \
                bf.u32[i] = __builtin_amdgcn_perm(hi, lo,                       \
                                0x0C040C00u + i * 0x00010001u) | 0x43004300u;   \
            accg[0][nh] = __builtin_amdgcn_mfma_f32_16x16x32_bf16(af0.s, bf.s8, \
                                                            accg[0][nh], 0, 0, 0);\
            accg[1][nh] = __builtin_amdgcn_mfma_f32_16x16x32_bf16(af1.s, bf.s8, \
                                                            accg[1][nh], 0, 0, 0);\
        }                                                                       \
    }                                                                           \
    _Pragma("unroll")                                                           \
    for (int nh = 0; nh < 2; ++nh) {                                            \
        const float zoff = (float)(((Z[st][nh] >>                               \
                        (((col0 + nh * 16 + n) & 7) * 4)) & 0xFu) + 129u);      \
        const float scl = S[st][nh];                                            \
        _Pragma("unroll")                                                       \
        for (int mt = 0; mt < 2; ++mt) {                                        \
            const float xr[4] = {XS[st][mt].x, XS[st][mt].y,                    \
                                 XS[st][mt].z, XS[st][mt].w};                   \
            _Pragma("unroll")                                                   \
            for (int r = 0; r < 4; ++r)                                         \
                acc[mt][nh][r] = fmaf(scl, fmaf(-zoff, xr[r],                   \
                                      accg[mt][nh][r]), acc[mt][nh][r]);        \
        }                                                                       \
    }                                                                           \
} while (0)

__global__ __launch_bounds__(256, 3) void main_kernel(
        const uint32_t* __restrict__ qw,
        const uint32_t* __restrict__ qz,
        const float* __restrict__ scales,
        const uint4* __restrict__ xf4,
        const float* __restrict__ xsumT,
        float* __restrict__ out) {
    const int tid  = threadIdx.x;
    const int wv   = tid >> 6;
    const int lane = tid & 63;
    const int n    = lane & 15;
    const int quad = lane >> 4;
    const int mh   = wv & 1;               // M-half: tiles {2mh, 2mh+1}
    const int cs   = wv >> 1;              // col-slice within block
    const int colblk = blockIdx.x >> 2;
    const int kseg   = blockIdx.x & 3;
    const int col0   = colblk * 64 + cs * 32;
    const int g0     = kseg * 8;

    const uint32_t* qwc = qw + col0 + n;

    float4v acc[2][2];
    #pragma unroll
    for (int mt = 0; mt < 2; ++mt)
        #pragma unroll
        for (int nh = 0; nh < 2; ++nh)
            acc[mt][nh] = (float4v){0.f, 0.f, 0.f, 0.f};

    uint4    A[2][8];
    uint32_t B[2][8];
    float4   XS[2][2];
    float    S[2][2];
    uint32_t Z[2][2];

    LOADG(0, g0);
    LOADG(1, g0 + 1);
    #pragma unroll
    for (int gi = 0; gi < 8; ++gi) {
        const int st = gi & 1;
        COMPUTEG(st);
        int gl = gi + 2; if (gl > 7) gl = 7;   // clamped tail refill (unused)
        LOADG(st, g0 + gl);
    }

    // split-K combine: 4 partials per output element
    #pragma unroll
    for (int mt = 0; mt < 2; ++mt)
        #pragma unroll
        for (int nh = 0; nh < 2; ++nh)
            #pragma unroll
            for (int r = 0; r < 4; ++r) {
                const int t = (mh * 2 + mt) * 16 + quad * 4 + r;
                atomicAdd(out + (size_t)t * OUT_F + col0 + nh * 16 + n,
                          acc[mt][nh][r]);
            }
}

// ---------------------------------------------------------------------------
extern "C" void kernel_launch(void* const* d_in, const int* in_sizes, int n_in,
                              void* d_out, int out_size, void* d_ws, size_t ws_size,
                              hipStream_t stream) {
    const float*    x      = (const float*)d_in[0];
    const uint32_t* qw     = (const uint32_t*)d_in[1];
    const uint32_t* qz     = (const uint32_t*)d_in[2];
    const float*    scales = (const float*)d_in[3];
    const float*    loraA  = (const float*)d_in[4];
    const float*    loraB  = (const float*)d_in[5];
    float* out = (float*)d_out;

    // ws layout: xf bf16-fragments [4][128][64] uint4 (512 KB) | xsumT | midT
    uint4* xf4   = (uint4*)d_ws;
    float* xsumT = (float*)((char*)d_ws + (size_t)TOKENS * IN_F * 2);
    float* midT  = xsumT + NG * TOKENS;

    prep_kernel<<<TOKENS, 256, 0, stream>>>(x, loraA, xf4, xsumT, midT);
    lora_out_kernel<<<(TOKENS * OUT_F) / 256, 256, 0, stream>>>(midT, loraB, out);
    main_kernel<<<(OUT_F / 64) * 4, 256, 0, stream>>>(qw, qz, scales, xf4, xsumT, out);
}